// Round 3
// baseline (6196.404 us; speedup 1.0000x reference)
//
#include <hip/hip_runtime.h>
#include <hip/hip_bf16.h>

#define B_ 32
#define T_ 512
#define E_ 256
#define H_ 512
#define L_ 50
#define NBLK 32          // worker blocks
#define NGRID 256        // workers + clock-pinning burner blocks

typedef __attribute__((ext_vector_type(8))) short short8;
typedef __attribute__((ext_vector_type(4))) float v4f;
typedef unsigned long long u64;

__device__ __forceinline__ unsigned short f2bf(float f){
    union { float f; unsigned u; } v; v.f = f;
    unsigned u = v.u;
    u += 0x7fffu + ((u >> 16) & 1u);   // RNE
    return (unsigned short)(u >> 16);
}
__device__ __forceinline__ float sigf(float x){ return 1.0f / (1.0f + expf(-x)); }

__device__ __forceinline__ float qredmax(float v){
    v = fmaxf(v, __shfl_xor(v, 1, 64));
    v = fmaxf(v, __shfl_xor(v, 2, 64));
    v = fmaxf(v, __shfl_xor(v, 4, 64));
    v = fmaxf(v, __shfl_xor(v, 8, 64));
    return v;
}
__device__ __forceinline__ float qredsum(float v){
    v += __shfl_xor(v, 1, 64);
    v += __shfl_xor(v, 2, 64);
    v += __shfl_xor(v, 4, 64);
    v += __shfl_xor(v, 8, 64);
    return v;
}

// ---------------------------------------------------------------- init
__global__ void init_kernel(const float* __restrict__ projW,
                            float* __restrict__ out,
                            unsigned int* __restrict__ cnt,     // [0]=done, rest scratch
                            unsigned int* __restrict__ flags,   // [T_][NBLK]
                            unsigned short* __restrict__ h0,
                            unsigned short* __restrict__ Wt)
{
    const int i = blockIdx.x * 256 + threadIdx.x;   // grid covers 32768
    if (i < 1024) cnt[i] = 0u;
    if (i < T_ * NBLK) flags[i] = 0u;
    if (i == 0) out[0] = 0.f;
    if (i < B_ * H_) h0[i] = 0;                     // h_all step 0 = zeros
    if (i < 64 * H_){                               // Wt[c][k] = proj_W[k][c], bf16, pad c>=50 with 0
        const int c = i >> 9;
        const int k = i & 511;
        const float v = (c < L_) ? projW[k * L_ + c] : 0.f;
        Wt[i] = f2bf(v);
    }
}

// ---------------------------------------------------------------- LSTM recurrence (cooperative)
// Blocks 0..31: workers (16 hc each). Blocks 32..255: clock-pinning burners —
// light dependent-FMA spin so DVFS keeps GFX clock at fmax while workers are
// latency-bound (round-2 evidence: 36ms cold dispatch => downclocking).
// Sync: per-block ready flags, plain agent-scope (sc0 sc1, L3-coherent) stores;
// consumers poll 32 flags with a per-wave ballot. No atomic RMW, no cache fences.
__global__ void __launch_bounds__(512, 2) lstm_kernel(
    const int* __restrict__ q, const int* __restrict__ lengths,
    const float* __restrict__ we, const float* __restrict__ lstmW,
    const float* __restrict__ lstmB,
    unsigned short* __restrict__ h_all, unsigned int* __restrict__ flags,
    unsigned int* __restrict__ done, float* __restrict__ sink)
{
    const int tid  = threadIdx.x;
    const int blk  = blockIdx.x;

    if (blk >= NBLK){
        // -------- burner: keep the CU busy (clock pin), negligible power
        float x = (float)tid;
        int guard = 0;
        for (;;){
            for (int i = 0; i < 256; ++i)
                x = __builtin_fmaf(x, 0.99999988f, 1.0e-7f);
            if (__hip_atomic_load(done, __ATOMIC_RELAXED, __HIP_MEMORY_SCOPE_AGENT) >= NBLK) break;
            if (++guard > (1 << 22)) break;   // safety valve
        }
        if (x == 1.2345e33f) sink[0] = x;     // defeat DCE; never taken
        return;
    }

    const int wv   = tid >> 6;          // 0..7
    const int lane = tid & 63;
    const int nt = wv & 1, mt = wv >> 1;  // mt 0..3
    const int l15 = lane & 15, quad = lane >> 4;

    // ---- A-operand mapping (lane&15 = m = z-col in tile; k = quad*8 + j)
    const int hcA  = blk * 16 + mt * 4 + (l15 >> 2);
    const int gA   = l15 & 3;
    const int colA = gA * H_ + hcA;     // column in lstm_W [768][2048]

    short8 AW[8], AH[16];
#pragma unroll
    for (int kc = 0; kc < 8; ++kc){     // x-part rows 0..255
        short8 f;
#pragma unroll
        for (int j = 0; j < 8; ++j){
            const int r = kc * 32 + quad * 8 + j;
            f[j] = (short)f2bf(lstmW[(size_t)r * 2048 + colA]);
        }
        AW[kc] = f;
    }
#pragma unroll
    for (int kc = 0; kc < 16; ++kc){    // h-part rows 256..767
        short8 f;
#pragma unroll
        for (int j = 0; j < 8; ++j){
            const int r = E_ + kc * 32 + quad * 8 + j;
            f[j] = (short)f2bf(lstmW[(size_t)r * 2048 + colA]);
        }
        AH[kc] = f;
    }

    // ---- epilogue mapping (lane&15 = n = batch; D row quad*4+reg -> hc=quad, gate=reg)
    const int bE  = nt * 16 + l15;
    const int hcE = blk * 16 + mt * 4 + quad;
    float bias4[4];
#pragma unroll
    for (int g = 0; g < 4; ++g) bias4[g] = lstmB[g * H_ + hcE];
    const int lenb = lengths[bE];

    float c_state = 0.f, h_prev = 0.f;

    // pre-loop x-part for t=0 (embedding gather + Wx MFMAs)
    v4f accX = { bias4[0], bias4[1], bias4[2], bias4[3] };
    {
        const int qv = q[bE * T_];
        const v4f* wp = (const v4f*)(we + (size_t)qv * E_);
#pragma unroll
        for (int kc = 0; kc < 8; ++kc){
            const v4f e0 = wp[kc * 8 + quad * 2];
            const v4f e1 = wp[kc * 8 + quad * 2 + 1];
            short8 eb;
#pragma unroll
            for (int j = 0; j < 4; ++j){ eb[j] = (short)f2bf(e0[j]); eb[4 + j] = (short)f2bf(e1[j]); }
            accX = __builtin_amdgcn_mfma_f32_16x16x32_bf16(AW[kc], eb, accX, 0, 0, 0);
        }
    }

    for (int t = 0; t < T_; ++t){
        if (t > 0){
            // per-wave flag poll: lanes 0..31 each watch one producer's flag
            const unsigned int* fl = flags + (unsigned)(t - 1) * NBLK;
            int guard = 0;
            for (;;){
                unsigned f = 1u;
                if (lane < NBLK)
                    f = __hip_atomic_load(fl + lane, __ATOMIC_RELAXED, __HIP_MEMORY_SCOPE_AGENT);
                if (__ballot(f != 0u) == 0xFFFFFFFFFFFFFFFFull) break;
                __builtin_amdgcn_s_sleep(1);
                if (++guard > (1 << 24)) break;   // safety valve
            }
            __builtin_amdgcn_fence(__ATOMIC_ACQUIRE, "workgroup");  // compiler ordering only
        }

        // h-part B-frags: 8B agent-relaxed loads (bypass L1/L2, read L3)
        const u64* hrow = (const u64*)(h_all + (size_t)t * (B_ * H_)) + (size_t)bE * (H_ / 4);
        u64 hl[32];
#pragma unroll
        for (int kc = 0; kc < 16; ++kc){
            hl[2 * kc]     = __hip_atomic_load(hrow + kc * 8 + quad * 2,     __ATOMIC_RELAXED, __HIP_MEMORY_SCOPE_AGENT);
            hl[2 * kc + 1] = __hip_atomic_load(hrow + kc * 8 + quad * 2 + 1, __ATOMIC_RELAXED, __HIP_MEMORY_SCOPE_AGENT);
        }
        v4f acc = accX, acc2 = { 0.f, 0.f, 0.f, 0.f };   // two chains halve MFMA dep latency
#pragma unroll
        for (int kc = 0; kc < 16; ++kc){
            union { u64 u[2]; short8 s; } cv;
            cv.u[0] = hl[2 * kc]; cv.u[1] = hl[2 * kc + 1];
            if (kc & 1) acc2 = __builtin_amdgcn_mfma_f32_16x16x32_bf16(AH[kc], cv.s, acc2, 0, 0, 0);
            else        acc  = __builtin_amdgcn_mfma_f32_16x16x32_bf16(AH[kc], cv.s, acc,  0, 0, 0);
        }

        // gates: i,j,f,o = acc[0..3]
        const float gi = acc[0] + acc2[0], gj = acc[1] + acc2[1];
        const float gf = acc[2] + acc2[2], go = acc[3] + acc2[3];
        const float c_new = c_state * sigf(gf + 1.0f) + sigf(gi) * tanhf(gj);
        const float h_new = tanhf(c_new) * sigf(go);
        const bool msk = (t < lenb);
        c_state = msk ? c_new : c_state;
        const float h2 = msk ? h_new : h_prev;           // dynamic_rnn copy-through
        h_prev = h2;

        // pack 4 hc (one per quad, same batch) into one u64, write-through to L3
        const unsigned hv = f2bf(h2);
        const int v0 = __shfl((int)hv, l15,      64);
        const int v1 = __shfl((int)hv, l15 + 16, 64);
        const int v2 = __shfl((int)hv, l15 + 32, 64);
        const int v3 = __shfl((int)hv, l15 + 48, 64);
        if (quad == 0){
            const u64 pk = (u64)(unsigned short)v0
                         | ((u64)(unsigned short)v1 << 16)
                         | ((u64)(unsigned short)v2 << 32)
                         | ((u64)(unsigned short)v3 << 48);
            u64* dst = (u64*)(h_all + (size_t)(t + 1) * (B_ * H_) + (size_t)bE * H_ + blk * 16 + mt * 4);
            __hip_atomic_store(dst, pk, __ATOMIC_RELAXED, __HIP_MEMORY_SCOPE_AGENT);
        }
        asm volatile("s_waitcnt vmcnt(0)" ::: "memory");  // h stores ack'd at L3
        __syncthreads();                                  // all waves of block done
        if (tid == 0)
            __hip_atomic_store(&flags[(unsigned)t * NBLK + blk], 1u,
                               __ATOMIC_RELAXED, __HIP_MEMORY_SCOPE_AGENT);

        // tail (in notify slack): x-part for t+1
        if (t + 1 < T_){
            accX = (v4f){ bias4[0], bias4[1], bias4[2], bias4[3] };
            const int qv = q[bE * T_ + t + 1];
            const v4f* wp = (const v4f*)(we + (size_t)qv * E_);
#pragma unroll
            for (int kc = 0; kc < 8; ++kc){
                const v4f e0 = wp[kc * 8 + quad * 2];
                const v4f e1 = wp[kc * 8 + quad * 2 + 1];
                short8 eb;
#pragma unroll
                for (int j = 0; j < 4; ++j){ eb[j] = (short)f2bf(e0[j]); eb[4 + j] = (short)f2bf(e1[j]); }
                accX = __builtin_amdgcn_mfma_f32_16x16x32_bf16(AW[kc], eb, accX, 0, 0, 0);
            }
        }
    }

    if (tid == 0)
        __hip_atomic_fetch_add(done, 1u, __ATOMIC_RELAXED, __HIP_MEMORY_SCOPE_AGENT);
}

// ---------------------------------------------------------------- projection + relu + log-softmax + xent
__global__ void __launch_bounds__(256) loss_kernel(
    const int* __restrict__ a, const int* __restrict__ lengths,
    const float* __restrict__ projB,
    const unsigned short* __restrict__ h_all,
    const unsigned short* __restrict__ Wt,
    float* __restrict__ out)
{
    const int tid = threadIdx.x;
    const int wv = tid >> 6, lane = tid & 63;
    const int l15 = lane & 15, quad = lane >> 4;
    const int wgid = blockIdx.x * 4 + wv;            // 0..1023
    const int row0 = wgid * 16;

    const int rowA = row0 + l15;
    const int bA = rowA >> 9, tA = rowA & 511;
    const unsigned short* hrow = h_all + ((size_t)(tA + 1) * B_ + bA) * H_;

    v4f acc[4] = { {0,0,0,0}, {0,0,0,0}, {0,0,0,0}, {0,0,0,0} };
#pragma unroll
    for (int kc = 0; kc < 16; ++kc){
        const short8 af = *(const short8*)(hrow + kc * 32 + quad * 8);
#pragma unroll
        for (int ntl = 0; ntl < 4; ++ntl){
            const short8 bf = *(const short8*)(Wt + (size_t)(ntl * 16 + l15) * H_ + kc * 32 + quad * 8);
            acc[ntl] = __builtin_amdgcn_mfma_f32_16x16x32_bf16(af, bf, acc[ntl], 0, 0, 0);
        }
    }

    float pb[4]; bool cv[4];
#pragma unroll
    for (int ntl = 0; ntl < 4; ++ntl){
        const int c = ntl * 16 + l15;
        cv[ntl] = (c < L_);
        pb[ntl] = cv[ntl] ? projB[c] : 0.f;
    }

#pragma unroll
    for (int r = 0; r < 4; ++r){
        const int row = row0 + quad * 4 + r;
        const int b = row >> 9, t = row & 511;
        const int len = lengths[b];
        const bool valid = (t < len);

        float lv[4];
#pragma unroll
        for (int ntl = 0; ntl < 4; ++ntl)
            lv[ntl] = fmaxf(acc[ntl][r] + pb[ntl], 0.f);   // relu(logits)

        float mx = -1e30f;
#pragma unroll
        for (int ntl = 0; ntl < 4; ++ntl) if (cv[ntl]) mx = fmaxf(mx, lv[ntl]);
        mx = qredmax(mx);
        float se = 0.f;
#pragma unroll
        for (int ntl = 0; ntl < 4; ++ntl) if (cv[ntl]) se += expf(lv[ntl] - mx);
        se = qredsum(se);
        const int lbl = a[row];
        float cand = 0.f;
#pragma unroll
        for (int ntl = 0; ntl < 4; ++ntl) if (ntl * 16 + l15 == lbl) cand = lv[ntl];
        const float llbl = qredsum(cand);

        if (valid && l15 == 0){
            const float xent = logf(se) + mx - llbl;      // -log_softmax[label]
            atomicAdd(out, xent / ((float)len * 32.0f));
        }
    }
}

// ---------------------------------------------------------------- launch
extern "C" void kernel_launch(void* const* d_in, const int* in_sizes, int n_in,
                              void* d_out, int out_size, void* d_ws, size_t ws_size,
                              hipStream_t stream)
{
    const int*   q   = (const int*)d_in[0];
    const int*   a   = (const int*)d_in[1];
    const int*   len = (const int*)d_in[2];
    const float* we  = (const float*)d_in[3];
    const float* lW  = (const float*)d_in[4];
    const float* lB  = (const float*)d_in[5];
    const float* pW  = (const float*)d_in[6];
    const float* pB  = (const float*)d_in[7];
    float* out = (float*)d_out;

    unsigned char* ws = (unsigned char*)d_ws;
    unsigned int*   cnt   = (unsigned int*)ws;                       // 4 KiB: [0]=done, [512..]=sink
    unsigned int*   flags = (unsigned int*)(ws + 4096);              // 512*32*4 = 64 KiB
    unsigned short* h_all = (unsigned short*)(ws + 4096 + 65536);    // 513*32*512*2 B
    unsigned short* Wt    = (unsigned short*)(ws + 4096 + 65536 + (size_t)(T_ + 1) * B_ * H_ * 2);

    init_kernel<<<dim3(128), dim3(256), 0, stream>>>(pW, out, cnt, flags, h_all, Wt);

    {
        const int* q_ = q; const int* len_ = len; const float* we_ = we;
        const float* lW_ = lW; const float* lB_ = lB;
        unsigned short* h_ = h_all; unsigned int* f_ = flags;
        unsigned int* d_ = cnt; float* s_ = (float*)(cnt + 512);
        void* args[] = { (void*)&q_, (void*)&len_, (void*)&we_, (void*)&lW_,
                         (void*)&lB_, (void*)&h_, (void*)&f_, (void*)&d_, (void*)&s_ };
        hipLaunchCooperativeKernel((void*)lstm_kernel, dim3(NGRID), dim3(512),
                                   args, 0, stream);
    }

    loss_kernel<<<dim3(256), dim3(256), 0, stream>>>(a, len, pB, h_all, Wt, out);
}

// Round 4
// 4415.556 us; speedup vs baseline: 1.4033x; 1.4033x over previous
//
#include <hip/hip_runtime.h>
#include <hip/hip_bf16.h>

#define B_ 32
#define T_ 512
#define E_ 256
#define H_ 512
#define L_ 50
#define NBLK 32

typedef __attribute__((ext_vector_type(8))) short short8;
typedef __attribute__((ext_vector_type(4))) float v4f;
typedef unsigned long long u64;

__device__ __forceinline__ unsigned short f2bf(float f){
    union { float f; unsigned u; } v; v.f = f;
    unsigned u = v.u;
    u += 0x7fffu + ((u >> 16) & 1u);   // RNE
    return (unsigned short)(u >> 16);
}
__device__ __forceinline__ float sigf(float x){ return 1.0f / (1.0f + expf(-x)); }

__device__ __forceinline__ float qredmax(float v){
    v = fmaxf(v, __shfl_xor(v, 1, 64));
    v = fmaxf(v, __shfl_xor(v, 2, 64));
    v = fmaxf(v, __shfl_xor(v, 4, 64));
    v = fmaxf(v, __shfl_xor(v, 8, 64));
    return v;
}
__device__ __forceinline__ float qredsum(float v){
    v += __shfl_xor(v, 1, 64);
    v += __shfl_xor(v, 2, 64);
    v += __shfl_xor(v, 4, 64);
    v += __shfl_xor(v, 8, 64);
    return v;
}

// ---------------------------------------------------------------- init
__global__ void init_kernel(const float* __restrict__ projW,
                            float* __restrict__ out,
                            unsigned int* __restrict__ cnt,     // scratch (cleared)
                            unsigned int* __restrict__ flags,   // [T_][NBLK]
                            unsigned short* __restrict__ h0,
                            unsigned short* __restrict__ Wt)
{
    const int i = blockIdx.x * 256 + threadIdx.x;   // grid covers 32768
    if (i < 1024) cnt[i] = 0u;
    if (i < T_ * NBLK) flags[i] = 0u;
    if (i == 0) out[0] = 0.f;
    if (i < B_ * H_) h0[i] = 0;                     // h_all step 0 = zeros
    if (i < 64 * H_){                               // Wt[c][k] = proj_W[k][c], bf16, pad c>=50 with 0
        const int c = i >> 9;
        const int k = i & 511;
        const float v = (c < L_) ? projW[k * L_ + c] : 0.f;
        Wt[i] = f2bf(v);
    }
}

// ---------------------------------------------------------------- LSTM recurrence (cooperative)
// Exchange protocol (round-4): h PRODUCTION is write-through (sc0 sc1 stores ->
// L3, vmcnt(0) drain, then a bypass flag store). h CONSUMPTION is normal cached
// 16B loads: each h_all[t] cache line is only ever touched post-flag, was never
// L1/L2-resident (written via L2-bypass stores only, fresh address每 step,
// 128B-aligned step regions), so the L2 miss fetches the fresh L3 data and
// duplicate wave reads hit cache instead of the fabric. Rounds 2/3 showed the
// per-lane 8B bypass loads (~131K fabric line-requests/step) were the ~12us/step
// bottleneck; flags stay bypass (a cached flag would never update).
__global__ void __launch_bounds__(512, 2) lstm_kernel(
    const int* __restrict__ q, const int* __restrict__ lengths,
    const float* __restrict__ we, const float* __restrict__ lstmW,
    const float* __restrict__ lstmB,
    unsigned short* __restrict__ h_all, unsigned int* __restrict__ flags)
{
    const int tid  = threadIdx.x;
    const int blk  = blockIdx.x;
    const int wv   = tid >> 6;          // 0..7
    const int lane = tid & 63;
    const int nt = wv & 1, mt = wv >> 1;  // mt 0..3
    const int l15 = lane & 15, quad = lane >> 4;

    // ---- A-operand mapping (lane&15 = m = z-col in tile; k = quad*8 + j)
    const int hcA  = blk * 16 + mt * 4 + (l15 >> 2);
    const int gA   = l15 & 3;
    const int colA = gA * H_ + hcA;     // column in lstm_W [768][2048]

    short8 AW[8], AH[16];
#pragma unroll
    for (int kc = 0; kc < 8; ++kc){     // x-part rows 0..255
        short8 f;
#pragma unroll
        for (int j = 0; j < 8; ++j){
            const int r = kc * 32 + quad * 8 + j;
            f[j] = (short)f2bf(lstmW[(size_t)r * 2048 + colA]);
        }
        AW[kc] = f;
    }
#pragma unroll
    for (int kc = 0; kc < 16; ++kc){    // h-part rows 256..767
        short8 f;
#pragma unroll
        for (int j = 0; j < 8; ++j){
            const int r = E_ + kc * 32 + quad * 8 + j;
            f[j] = (short)f2bf(lstmW[(size_t)r * 2048 + colA]);
        }
        AH[kc] = f;
    }

    // ---- epilogue mapping (lane&15 = n = batch; D row quad*4+reg -> hc=quad, gate=reg)
    const int bE  = nt * 16 + l15;
    const int hcE = blk * 16 + mt * 4 + quad;
    float bias4[4];
#pragma unroll
    for (int g = 0; g < 4; ++g) bias4[g] = lstmB[g * H_ + hcE];
    const int lenb = lengths[bE];

    float c_state = 0.f, h_prev = 0.f;

    // pre-loop x-part for t=0 (embedding gather + Wx MFMAs)
    v4f accX = { bias4[0], bias4[1], bias4[2], bias4[3] };
    {
        const int qv = q[bE * T_];
        const v4f* wp = (const v4f*)(we + (size_t)qv * E_);
#pragma unroll
        for (int kc = 0; kc < 8; ++kc){
            const v4f e0 = wp[kc * 8 + quad * 2];
            const v4f e1 = wp[kc * 8 + quad * 2 + 1];
            short8 eb;
#pragma unroll
            for (int j = 0; j < 4; ++j){ eb[j] = (short)f2bf(e0[j]); eb[4 + j] = (short)f2bf(e1[j]); }
            accX = __builtin_amdgcn_mfma_f32_16x16x32_bf16(AW[kc], eb, accX, 0, 0, 0);
        }
    }

    for (int t = 0; t < T_; ++t){
        if (t > 0){
            // per-wave flag poll: lanes 0..31 each watch one producer's flag (bypass loads)
            const unsigned int* fl = flags + (unsigned)(t - 1) * NBLK;
            int guard = 0;
            for (;;){
                unsigned f = 1u;
                if (lane < NBLK)
                    f = __hip_atomic_load(fl + lane, __ATOMIC_RELAXED, __HIP_MEMORY_SCOPE_AGENT);
                if (__ballot(f != 0u) == 0xFFFFFFFFFFFFFFFFull) break;
                __builtin_amdgcn_s_sleep(1);
                if (++guard > (1 << 24)) break;   // safety valve
            }
            __builtin_amdgcn_fence(__ATOMIC_ACQUIRE, "workgroup");  // ordering only (no cache ops)
        }

        // h-part B-frags: normal cached 16B loads (see protocol note above)
        const unsigned short* hrow = h_all + (size_t)t * (B_ * H_) + (size_t)bE * H_;
        v4f acc = accX, acc2 = { 0.f, 0.f, 0.f, 0.f };   // two chains halve MFMA dep latency
#pragma unroll
        for (int kc = 0; kc < 16; ++kc){
            const short8 hb = *(const short8*)(hrow + kc * 32 + quad * 8);
            if (kc & 1) acc2 = __builtin_amdgcn_mfma_f32_16x16x32_bf16(AH[kc], hb, acc2, 0, 0, 0);
            else        acc  = __builtin_amdgcn_mfma_f32_16x16x32_bf16(AH[kc], hb, acc,  0, 0, 0);
        }

        // gates: i,j,f,o = acc[0..3]
        const float gi = acc[0] + acc2[0], gj = acc[1] + acc2[1];
        const float gf = acc[2] + acc2[2], go = acc[3] + acc2[3];
        const float c_new = c_state * sigf(gf + 1.0f) + sigf(gi) * tanhf(gj);
        const float h_new = tanhf(c_new) * sigf(go);
        const bool msk = (t < lenb);
        c_state = msk ? c_new : c_state;
        const float h2 = msk ? h_new : h_prev;           // dynamic_rnn copy-through
        h_prev = h2;

        // pack 4 hc (one per quad, same batch) into one u64, write-through to L3
        const unsigned hv = f2bf(h2);
        const int v0 = __shfl((int)hv, l15,      64);
        const int v1 = __shfl((int)hv, l15 + 16, 64);
        const int v2 = __shfl((int)hv, l15 + 32, 64);
        const int v3 = __shfl((int)hv, l15 + 48, 64);
        if (quad == 0){
            const u64 pk = (u64)(unsigned short)v0
                         | ((u64)(unsigned short)v1 << 16)
                         | ((u64)(unsigned short)v2 << 32)
                         | ((u64)(unsigned short)v3 << 48);
            u64* dst = (u64*)(h_all + (size_t)(t + 1) * (B_ * H_) + (size_t)bE * H_ + blk * 16 + mt * 4);
            __hip_atomic_store(dst, pk, __ATOMIC_RELAXED, __HIP_MEMORY_SCOPE_AGENT);
        }
        asm volatile("s_waitcnt vmcnt(0)" ::: "memory");  // h stores ack'd at L3
        __syncthreads();                                  // all waves of block done
        if (tid == 0)
            __hip_atomic_store(&flags[(unsigned)t * NBLK + blk], 1u,
                               __ATOMIC_RELAXED, __HIP_MEMORY_SCOPE_AGENT);

        // tail (in notify slack): x-part for t+1 (normal cached loads)
        if (t + 1 < T_){
            accX = (v4f){ bias4[0], bias4[1], bias4[2], bias4[3] };
            const int qv = q[bE * T_ + t + 1];
            const v4f* wp = (const v4f*)(we + (size_t)qv * E_);
#pragma unroll
            for (int kc = 0; kc < 8; ++kc){
                const v4f e0 = wp[kc * 8 + quad * 2];
                const v4f e1 = wp[kc * 8 + quad * 2 + 1];
                short8 eb;
#pragma unroll
                for (int j = 0; j < 4; ++j){ eb[j] = (short)f2bf(e0[j]); eb[4 + j] = (short)f2bf(e1[j]); }
                accX = __builtin_amdgcn_mfma_f32_16x16x32_bf16(AW[kc], eb, accX, 0, 0, 0);
            }
        }
    }
}

// ---------------------------------------------------------------- projection + relu + log-softmax + xent
__global__ void __launch_bounds__(256) loss_kernel(
    const int* __restrict__ a, const int* __restrict__ lengths,
    const float* __restrict__ projB,
    const unsigned short* __restrict__ h_all,
    const unsigned short* __restrict__ Wt,
    float* __restrict__ out)
{
    const int tid = threadIdx.x;
    const int wv = tid >> 6, lane = tid & 63;
    const int l15 = lane & 15, quad = lane >> 4;
    const int wgid = blockIdx.x * 4 + wv;            // 0..1023
    const int row0 = wgid * 16;

    const int rowA = row0 + l15;
    const int bA = rowA >> 9, tA = rowA & 511;
    const unsigned short* hrow = h_all + ((size_t)(tA + 1) * B_ + bA) * H_;

    v4f acc[4] = { {0,0,0,0}, {0,0,0,0}, {0,0,0,0}, {0,0,0,0} };
#pragma unroll
    for (int kc = 0; kc < 16; ++kc){
        const short8 af = *(const short8*)(hrow + kc * 32 + quad * 8);
#pragma unroll
        for (int ntl = 0; ntl < 4; ++ntl){
            const short8 bf = *(const short8*)(Wt + (size_t)(ntl * 16 + l15) * H_ + kc * 32 + quad * 8);
            acc[ntl] = __builtin_amdgcn_mfma_f32_16x16x32_bf16(af, bf, acc[ntl], 0, 0, 0);
        }
    }

    float pb[4]; bool cv[4];
#pragma unroll
    for (int ntl = 0; ntl < 4; ++ntl){
        const int c = ntl * 16 + l15;
        cv[ntl] = (c < L_);
        pb[ntl] = cv[ntl] ? projB[c] : 0.f;
    }

#pragma unroll
    for (int r = 0; r < 4; ++r){
        const int row = row0 + quad * 4 + r;
        const int b = row >> 9, t = row & 511;
        const int len = lengths[b];
        const bool valid = (t < len);

        float lv[4];
#pragma unroll
        for (int ntl = 0; ntl < 4; ++ntl)
            lv[ntl] = fmaxf(acc[ntl][r] + pb[ntl], 0.f);   // relu(logits)

        float mx = -1e30f;
#pragma unroll
        for (int ntl = 0; ntl < 4; ++ntl) if (cv[ntl]) mx = fmaxf(mx, lv[ntl]);
        mx = qredmax(mx);
        float se = 0.f;
#pragma unroll
        for (int ntl = 0; ntl < 4; ++ntl) if (cv[ntl]) se += expf(lv[ntl] - mx);
        se = qredsum(se);
        const int lbl = a[row];
        float cand = 0.f;
#pragma unroll
        for (int ntl = 0; ntl < 4; ++ntl) if (ntl * 16 + l15 == lbl) cand = lv[ntl];
        const float llbl = qredsum(cand);

        if (valid && l15 == 0){
            const float xent = logf(se) + mx - llbl;      // -log_softmax[label]
            atomicAdd(out, xent / ((float)len * 32.0f));
        }
    }
}

// ---------------------------------------------------------------- launch
extern "C" void kernel_launch(void* const* d_in, const int* in_sizes, int n_in,
                              void* d_out, int out_size, void* d_ws, size_t ws_size,
                              hipStream_t stream)
{
    const int*   q   = (const int*)d_in[0];
    const int*   a   = (const int*)d_in[1];
    const int*   len = (const int*)d_in[2];
    const float* we  = (const float*)d_in[3];
    const float* lW  = (const float*)d_in[4];
    const float* lB  = (const float*)d_in[5];
    const float* pW  = (const float*)d_in[6];
    const float* pB  = (const float*)d_in[7];
    float* out = (float*)d_out;

    unsigned char* ws = (unsigned char*)d_ws;
    unsigned int*   cnt   = (unsigned int*)ws;                       // 4 KiB scratch
    unsigned int*   flags = (unsigned int*)(ws + 4096);              // 512*32*4 = 64 KiB
    unsigned short* h_all = (unsigned short*)(ws + 4096 + 65536);    // 513*32*512*2 B
    unsigned short* Wt    = (unsigned short*)(ws + 4096 + 65536 + (size_t)(T_ + 1) * B_ * H_ * 2);

    init_kernel<<<dim3(128), dim3(256), 0, stream>>>(pW, out, cnt, flags, h_all, Wt);

    {
        const int* q_ = q; const int* len_ = len; const float* we_ = we;
        const float* lW_ = lW; const float* lB_ = lB;
        unsigned short* h_ = h_all; unsigned int* f_ = flags;
        void* args[] = { (void*)&q_, (void*)&len_, (void*)&we_, (void*)&lW_,
                         (void*)&lB_, (void*)&h_, (void*)&f_ };
        hipLaunchCooperativeKernel((void*)lstm_kernel, dim3(NBLK), dim3(512),
                                   args, 0, stream);
    }

    loss_kernel<<<dim3(256), dim3(256), 0, stream>>>(a, len, pB, h_all, Wt, out);
}